// Round 8
// baseline (225.527 us; speedup 1.0000x reference)
//
#include <hip/hip_runtime.h>

typedef float f32x4 __attribute__((ext_vector_type(4)));

#define T_LEN 2048
#define GROUP 16
#define NG    (T_LEN / GROUP)   /* 128 groups */
#define CH    12                /* 16B chunks per lane per group */
#define KH    28.853901f        /* 20*log2(e): h(x) = 1/(1+exp2(-KH*x)) */

__device__ __forceinline__ float hs_neg(float negKx) {
    float e = __builtin_amdgcn_exp2f(negKx);
    return __builtin_amdgcn_rcpf(1.0f + e);
}

#define WAITV(N) asm volatile("s_waitcnt vmcnt(" #N ")" ::: "memory")
#define CFENCE() asm volatile("" ::: "memory")

/* acquire: poll producer counter until >= val (volatile ds_read each probe) */
__device__ __forceinline__ void wait_ge(volatile int* f, int val) {
    while (*f < val) __builtin_amdgcn_s_sleep(1);
}
/* release: drain own LDS writes, then bump counter */
__device__ __forceinline__ void publish(volatile int* f, int val) {
    asm volatile("s_waitcnt lgkmcnt(0)" ::: "memory");
    *f = val;
}

#define DMA_GROUP(SLOT, G) do {                                                \
    const float* g_ = row + (size_t)(G) * (3 * GROUP);                         \
    _Pragma("unroll")                                                          \
    for (int j_ = 0; j_ < CH; ++j_) {                                          \
        __builtin_amdgcn_global_load_lds(                                      \
            (const __attribute__((address_space(1))) void*)(g_ + 4 * j_),      \
            (__attribute__((address_space(3))) void*)&s_in[SLOT][j_][0],       \
            16, 0, 0);                                                         \
    } } while (0)

__global__ __launch_bounds__(256, 1)
void xaj_flag_kernel(const float* __restrict__ inp,
                     const float* __restrict__ p_wum,
                     const float* __restrict__ p_wlm,
                     const float* __restrict__ p_wdm,
                     const float* __restrict__ p_c,
                     const float* __restrict__ p_b,
                     const float* __restrict__ p_k1,
                     const float* __restrict__ p_k2,
                     const float* __restrict__ p_k3,
                     float* __restrict__ out)
{
    /* Rings (audited):
       s_in  ring-3: only W0 reads; slots {g, g+1 in flight, g+2 issue} distinct.
       s_rem/s_d1 ring-2: W1 consumes lag-0; W0 overwrite at G needs c1>=G-1.
       s_u/s_d2  ring-2: W2 lag-0 from W1; W1 overwrite at G needs c2>=G-1.
       s_wd      ring-2: W3 lag-0 from W2; W2 overwrite at G needs c3>=G-1.
       s_wu/s_p  ring-4: W3 reads group g; W0 overwrite at G needs c3>=G-3. */
    __shared__ f32x4 s_in [3][CH][64];        /* 36 KB */
    __shared__ float s_rem[2][GROUP][64];
    __shared__ float s_d1 [2][GROUP][64];
    __shared__ float s_u  [2][GROUP][64];
    __shared__ float s_d2 [2][GROUP][64];
    __shared__ float s_wd [2][GROUP][64];
    __shared__ float s_wu [4][GROUP][64];
    __shared__ float s_p  [4][GROUP][64];
    __shared__ int   s_c[4];                  /* per-wave completed-group count */

    const int lane  = threadIdx.x & 63;
    const int wv    = threadIdx.x >> 6;
    const int chain = blockIdx.x * 64 + lane;
    const float* __restrict__ row = inp + (size_t)chain * (3 * T_LEN);
    float* __restrict__ orow      = out + (size_t)chain * T_LEN;

    const float wum = p_wum[0], wlm = p_wlm[0], wdm = p_wdm[0];
    const float cc  = p_c[0],   bb  = p_b[0];
    const float k1  = p_k1[0],  k2  = p_k2[0],  k3 = p_k3[0];

    /* runoff_production called as (wu, wd, wl, p, wum, wdm, wlm, b, c) */
    const float w_total = (wum * 19.9f + 0.1f)
                        + (wdm * 30.0f + 60.0f)
                        + (wlm * 60.0f + 60.0f);
    const float inv_wt = 1.0f / w_total;
    const float c_s = cc * 0.19f + 0.01f;
    const float b_s = bb * 0.3f  + 0.1f;
    const float k1s = k1 * 0.69f + 0.01f;
    const float k2s = k2 * 0.69f + 0.01f;
    const float k3s = k3 * 0.89f + 0.01f;
    const float Kq = k1s + 0.5f * k2s * (1.0f - k1s)
                   + 0.25f * k3s * (1.0f - k1s) * (1.0f - k2s);

    if (threadIdx.x < 4) s_c[threadIdx.x] = 0;
    __syncthreads();               /* nothing in flight yet: safe */

    volatile int* vc = s_c;

    if (wv == 0) {
        /* ---- W0: wu-chain (et1, rem) + input DMA ---- */
        float wu = 0.0f;
        DMA_GROUP(0, 0);
        DMA_GROUP(1, 1);
        for (int g = 0; g < NG; ++g) {
            if (g >= 2) wait_ge(vc + 1, g - 1);   /* rem/d1 ring-2 */
            if (g >= 4) wait_ge(vc + 3, g - 3);   /* wu/p ring-4 */
            if (g < NG - 1) { WAITV(12); } else { WAITV(0); }
            CFENCE();
            if (g + 2 < NG) DMA_GROUP((g + 2) % 3, g + 2);
            f32x4 fv[CH];
            const int s3 = g % 3;
#pragma unroll
            for (int j = 0; j < CH; ++j) fv[j] = s_in[s3][j][lane];
#pragma unroll
            for (int j = 0; j < GROUP; ++j) {
                float pet = fv[(3*j)   >> 2][(3*j)   & 3];
                float p   = fv[(3*j+2) >> 2][(3*j+2) & 3];
                float dwp = pet - wu;
                float a   = hs_neg(KH * dwp);          /* h(wu-pet), chained */
                float y   = dwp - a * dwp;             /* pet - et1 */
                float hx  = hs_neg(-KH * y);           /* h(pet-et1), ILP */
                float rem = hx * y;
                float wun = fmaf(-a, dwp, p);          /* wu+p-et1 */
                float d1  = wun - wu;
                wu = wun;
                s_rem[g & 1][j][lane] = rem;
                s_d1 [g & 1][j][lane] = d1;
                s_wu [g & 3][j][lane] = wun;
                s_p  [g & 3][j][lane] = p;
            }
            publish(vc + 0, g + 1);
        }
    } else if (wv == 1) {
        /* ---- W1: wl-chain (et2) ---- */
        float wl = 0.0f;
        for (int g = 0; g < NG; ++g) {
            wait_ge(vc + 0, g + 1);
            if (g >= 2) wait_ge(vc + 2, g - 1);   /* u/d2 ring-2 */
            CFENCE();
            float remv[GROUP], d1v[GROUP];
#pragma unroll
            for (int j = 0; j < GROUP; ++j) {
                remv[j] = s_rem[g & 1][j][lane];
                d1v [j] = s_d1 [g & 1][j][lane];
            }
#pragma unroll
            for (int j = 0; j < GROUP; ++j) {
                float rem  = remv[j], d1 = d1v[j];
                float nKr  = -KH * rem;
                float b2   = hs_neg(fmaf(KH, wl, nKr));  /* h(rem-wl), chained */
                float hrem = hs_neg(nKr);                /* h(rem), ILP */
                float et22 = fmaf(b2, wl - rem, rem);
                float et2  = hrem * et22;
                float wld1 = wl + d1;
                wl = fmaf(-hrem, et22, wld1);            /* wl+d1-et2 */
                s_u [g & 1][j][lane] = rem - et2;
                s_d2[g & 1][j][lane] = d1 - et2;
            }
            publish(vc + 1, g + 1);
        }
    } else if (wv == 2) {
        /* ---- W2: wd-chain (et3) ---- */
        float wd = 0.0f;
        for (int g = 0; g < NG; ++g) {
            wait_ge(vc + 1, g + 1);
            if (g >= 2) wait_ge(vc + 3, g - 1);   /* wd ring-2 */
            CFENCE();
            float uv[GROUP], d2v[GROUP];
#pragma unroll
            for (int j = 0; j < GROUP; ++j) {
                uv [j] = s_u [g & 1][j][lane];
                d2v[j] = s_d2[g & 1][j][lane];
            }
#pragma unroll
            for (int j = 0; j < GROUP; ++j) {
                float u   = uv[j], d2 = d2v[j];
                float nKu = -KH * u;
                float c2  = hs_neg(fmaf(KH, wd, nKu));   /* h(u-wd), chained */
                float hu  = hs_neg(nKu);                 /* h(u), ILP */
                float et33 = fmaf(c2, wd - u, u);
                float wdd2 = wd + d2;
                wd = fmaf(-hu, et33, wdd2);              /* wd+d2-et3 */
                s_wd[g & 1][j][lane] = wd;
            }
            publish(vc + 2, g + 1);
        }
    } else {
        /* ---- W3: stateless output ---- */
        for (int g = 0; g < NG; ++g) {
            wait_ge(vc + 2, g + 1);   /* implies c0 >= g+1 transitively */
            CFENCE();
            float qv[GROUP];
#pragma unroll
            for (int j = 0; j < GROUP; ++j) {
                float wuv = s_wu[g & 3][j][lane];
                float wdv = s_wd[g & 1][j][lane];
                float p   = s_p [g & 3][j][lane];
                float ru = wuv * inv_wt;
                float rd = wdv * inv_wt;
                float s2 = fmaf(c_s * ru, ru, (b_s * rd) * rd);
                float ps = p - s2;
                float so = hs_neg(-KH * ps);             /* h(ps) */
                qv[j] = ps * so * Kq;
            }
            f32x4* o4 = (f32x4*)(orow + (size_t)g * GROUP);
#pragma unroll
            for (int i = 0; i < GROUP / 4; ++i) {
                f32x4 q = {qv[4*i], qv[4*i+1], qv[4*i+2], qv[4*i+3]};
                o4[i] = q;
            }
            publish(vc + 3, g + 1);
        }
    }
}

extern "C" void kernel_launch(void* const* d_in, const int* in_sizes, int n_in,
                              void* d_out, int out_size, void* d_ws, size_t ws_size,
                              hipStream_t stream) {
    const float* inp = (const float*)d_in[0];
    const int B = out_size / T_LEN;            // 4096
    dim3 block(256), grid(B / 64);
    xaj_flag_kernel<<<grid, block, 0, stream>>>(
        inp,
        (const float*)d_in[1],  // wum
        (const float*)d_in[2],  // wlm
        (const float*)d_in[3],  // wdm
        (const float*)d_in[4],  // c
        (const float*)d_in[5],  // b
        (const float*)d_in[6],  // k1
        (const float*)d_in[7],  // k2
        (const float*)d_in[8],  // k3
        (float*)d_out);
}

// Round 9
// 219.830 us; speedup vs baseline: 1.0259x; 1.0259x over previous
//
#include <hip/hip_runtime.h>

typedef float f32x4 __attribute__((ext_vector_type(4)));

#define T_LEN 2048
#define GROUP 16
#define NG    (T_LEN / GROUP)   /* 128 groups */
#define CH    12                /* 16B chunks per lane per group */
#define KH    28.853901f        /* 20*log2(e): h(x) = 1/(1+exp2(-KH*x)) */

__device__ __forceinline__ float hs_neg(float negKx) {
    float e = __builtin_amdgcn_exp2f(negKx);
    return __builtin_amdgcn_rcpf(1.0f + e);
}

#define WAITV(N) asm volatile("s_waitcnt vmcnt(" #N ")" ::: "memory")
#define CFENCE() __builtin_amdgcn_sched_barrier(0)

/* acquire: poll flag (ds_read_b32 via workgroup-scope relaxed atomic on LDS).
   Dependent ds_reads can only issue after the branch consumes the flag value,
   so in-wave ordering is sufficient; CFENCE blocks compiler reordering. */
__device__ __forceinline__ void wait_ge(int* f, int val) {
    while (__hip_atomic_load(f, __ATOMIC_RELAXED, __HIP_MEMORY_SCOPE_WORKGROUP) < val) {}
    CFENCE();
}
/* release: drain own LDS writes (lgkmcnt only -- NOT vmcnt: must not drain
   the DMA prefetch queue), then bump counter with a relaxed ds_write. */
__device__ __forceinline__ void publish(int* f, int val) {
    asm volatile("s_waitcnt lgkmcnt(0)" ::: "memory");
    __hip_atomic_store(f, val, __ATOMIC_RELAXED, __HIP_MEMORY_SCOPE_WORKGROUP);
}

#define DMA_GROUP(SLOT, G) do {                                                \
    const float* g_ = row + (size_t)(G) * (3 * GROUP);                         \
    _Pragma("unroll")                                                          \
    for (int j_ = 0; j_ < CH; ++j_) {                                          \
        __builtin_amdgcn_global_load_lds(                                      \
            (const __attribute__((address_space(1))) void*)(g_ + 4 * j_),      \
            (__attribute__((address_space(3))) void*)&s_in[SLOT][j_][0],       \
            16, 0, 0);                                                         \
    } } while (0)

__global__ __launch_bounds__(256, 1)
void xaj_flag2_kernel(const float* __restrict__ inp,
                      const float* __restrict__ p_wum,
                      const float* __restrict__ p_wlm,
                      const float* __restrict__ p_wdm,
                      const float* __restrict__ p_c,
                      const float* __restrict__ p_b,
                      const float* __restrict__ p_k1,
                      const float* __restrict__ p_k2,
                      const float* __restrict__ p_k3,
                      float* __restrict__ out)
{
    /* Rings (audited):
       s_in  ring-3: only W0 reads; slots {g, g+1 in flight, g+2 issue} distinct.
       s_rem/s_d1 ring-2: W0 overwrite at G needs c1>=G-1.
       s_u/s_d2  ring-2: W1 overwrite at G needs c2>=G-1.
       s_wd      ring-2: W2 overwrite at G needs c3>=G-1.
       s_wu/s_p  ring-4: W0 overwrite at G needs c3>=G-3. */
    __shared__ f32x4 s_in [3][CH][64];        /* 36 KB */
    __shared__ float s_rem[2][GROUP][64];
    __shared__ float s_d1 [2][GROUP][64];
    __shared__ float s_u  [2][GROUP][64];
    __shared__ float s_d2 [2][GROUP][64];
    __shared__ float s_wd [2][GROUP][64];
    __shared__ float s_wu [4][GROUP][64];
    __shared__ float s_p  [4][GROUP][64];
    __shared__ int   s_c[4];                  /* per-wave completed-group count */

    const int lane  = threadIdx.x & 63;
    const int wv    = threadIdx.x >> 6;
    const int chain = blockIdx.x * 64 + lane;
    const float* __restrict__ row = inp + (size_t)chain * (3 * T_LEN);
    float* __restrict__ orow      = out + (size_t)chain * T_LEN;

    const float wum = p_wum[0], wlm = p_wlm[0], wdm = p_wdm[0];
    const float cc  = p_c[0],   bb  = p_b[0];
    const float k1  = p_k1[0],  k2  = p_k2[0],  k3 = p_k3[0];

    /* runoff_production called as (wu, wd, wl, p, wum, wdm, wlm, b, c) */
    const float w_total = (wum * 19.9f + 0.1f)
                        + (wdm * 30.0f + 60.0f)
                        + (wlm * 60.0f + 60.0f);
    const float inv_wt = 1.0f / w_total;
    const float c_s = cc * 0.19f + 0.01f;
    const float b_s = bb * 0.3f  + 0.1f;
    const float k1s = k1 * 0.69f + 0.01f;
    const float k2s = k2 * 0.69f + 0.01f;
    const float k3s = k3 * 0.89f + 0.01f;
    const float Kq = k1s + 0.5f * k2s * (1.0f - k1s)
                   + 0.25f * k3s * (1.0f - k1s) * (1.0f - k2s);

    if (threadIdx.x < 4) s_c[threadIdx.x] = 0;
    __syncthreads();               /* nothing in flight yet: safe */

    if (wv == 0) {
        /* ---- W0: wu-chain (et1, rem) + input DMA ---- */
        float wu = 0.0f;
        DMA_GROUP(0, 0);
        DMA_GROUP(1, 1);
        for (int g = 0; g < NG; ++g) {
            if (g >= 2) wait_ge(&s_c[1], g - 1);   /* rem/d1 ring-2 */
            if (g >= 4) wait_ge(&s_c[3], g - 3);   /* wu/p ring-4 */
            if (g < NG - 1) { WAITV(12); } else { WAITV(0); }
            CFENCE();
            if (g + 2 < NG) DMA_GROUP((g + 2) % 3, g + 2);
            f32x4 fv[CH];
            const int s3 = g % 3;
#pragma unroll
            for (int j = 0; j < CH; ++j) fv[j] = s_in[s3][j][lane];
#pragma unroll
            for (int j = 0; j < GROUP; ++j) {
                float pet = fv[(3*j)   >> 2][(3*j)   & 3];
                float p   = fv[(3*j+2) >> 2][(3*j+2) & 3];
                float dwp = pet - wu;
                float a   = hs_neg(KH * dwp);          /* h(wu-pet), chained */
                float y   = dwp - a * dwp;             /* pet - et1 */
                float hx  = hs_neg(-KH * y);           /* h(pet-et1), ILP */
                float rem = hx * y;
                float wun = fmaf(-a, dwp, p);          /* wu+p-et1 */
                float d1  = wun - wu;
                wu = wun;
                s_rem[g & 1][j][lane] = rem;
                s_d1 [g & 1][j][lane] = d1;
                s_wu [g & 3][j][lane] = wun;
                s_p  [g & 3][j][lane] = p;
            }
            publish(&s_c[0], g + 1);
        }
    } else if (wv == 1) {
        /* ---- W1: wl-chain (et2) ---- */
        float wl = 0.0f;
        for (int g = 0; g < NG; ++g) {
            wait_ge(&s_c[0], g + 1);
            if (g >= 2) wait_ge(&s_c[2], g - 1);   /* u/d2 ring-2 */
            float remv[GROUP], d1v[GROUP];
#pragma unroll
            for (int j = 0; j < GROUP; ++j) {
                remv[j] = s_rem[g & 1][j][lane];
                d1v [j] = s_d1 [g & 1][j][lane];
            }
#pragma unroll
            for (int j = 0; j < GROUP; ++j) {
                float rem  = remv[j], d1 = d1v[j];
                float nKr  = -KH * rem;
                float b2   = hs_neg(fmaf(KH, wl, nKr));  /* h(rem-wl), chained */
                float hrem = hs_neg(nKr);                /* h(rem), ILP */
                float et22 = fmaf(b2, wl - rem, rem);
                float et2  = hrem * et22;
                float wld1 = wl + d1;
                wl = fmaf(-hrem, et22, wld1);            /* wl+d1-et2 */
                s_u [g & 1][j][lane] = rem - et2;
                s_d2[g & 1][j][lane] = d1 - et2;
            }
            publish(&s_c[1], g + 1);
        }
    } else if (wv == 2) {
        /* ---- W2: wd-chain (et3) ---- */
        float wd = 0.0f;
        for (int g = 0; g < NG; ++g) {
            wait_ge(&s_c[1], g + 1);
            if (g >= 2) wait_ge(&s_c[3], g - 1);   /* wd ring-2 */
            float uv[GROUP], d2v[GROUP];
#pragma unroll
            for (int j = 0; j < GROUP; ++j) {
                uv [j] = s_u [g & 1][j][lane];
                d2v[j] = s_d2[g & 1][j][lane];
            }
#pragma unroll
            for (int j = 0; j < GROUP; ++j) {
                float u   = uv[j], d2 = d2v[j];
                float nKu = -KH * u;
                float c2  = hs_neg(fmaf(KH, wd, nKu));   /* h(u-wd), chained */
                float hu  = hs_neg(nKu);                 /* h(u), ILP */
                float et33 = fmaf(c2, wd - u, u);
                float wdd2 = wd + d2;
                wd = fmaf(-hu, et33, wdd2);              /* wd+d2-et3 */
                s_wd[g & 1][j][lane] = wd;
            }
            publish(&s_c[2], g + 1);
        }
    } else {
        /* ---- W3: stateless output ---- */
        for (int g = 0; g < NG; ++g) {
            wait_ge(&s_c[2], g + 1);   /* implies c0 >= g+1 transitively */
            float qv[GROUP];
#pragma unroll
            for (int j = 0; j < GROUP; ++j) {
                float wuv = s_wu[g & 3][j][lane];
                float wdv = s_wd[g & 1][j][lane];
                float p   = s_p [g & 3][j][lane];
                float ru = wuv * inv_wt;
                float rd = wdv * inv_wt;
                float s2 = fmaf(c_s * ru, ru, (b_s * rd) * rd);
                float ps = p - s2;
                float so = hs_neg(-KH * ps);             /* h(ps) */
                qv[j] = ps * so * Kq;
            }
            f32x4* o4 = (f32x4*)(orow + (size_t)g * GROUP);
#pragma unroll
            for (int i = 0; i < GROUP / 4; ++i) {
                f32x4 q = {qv[4*i], qv[4*i+1], qv[4*i+2], qv[4*i+3]};
                o4[i] = q;
            }
            publish(&s_c[3], g + 1);
        }
    }
}

extern "C" void kernel_launch(void* const* d_in, const int* in_sizes, int n_in,
                              void* d_out, int out_size, void* d_ws, size_t ws_size,
                              hipStream_t stream) {
    const float* inp = (const float*)d_in[0];
    const int B = out_size / T_LEN;            // 4096
    dim3 block(256), grid(B / 64);
    xaj_flag2_kernel<<<grid, block, 0, stream>>>(
        inp,
        (const float*)d_in[1],  // wum
        (const float*)d_in[2],  // wlm
        (const float*)d_in[3],  // wdm
        (const float*)d_in[4],  // c
        (const float*)d_in[5],  // b
        (const float*)d_in[6],  // k1
        (const float*)d_in[7],  // k2
        (const float*)d_in[8],  // k3
        (float*)d_out);
}

// Round 11
// 134.286 us; speedup vs baseline: 1.6795x; 1.6370x over previous
//
#include <hip/hip_runtime.h>

typedef float  f32x4 __attribute__((ext_vector_type(4)));
typedef __fp16 f16x2 __attribute__((ext_vector_type(2)));

#define T_LEN 2048
#define GROUP 32
#define NG    (T_LEN / GROUP)      /* 64 groups */
#define NT    (NG + 3)             /* 67 ticks, 4-stage lockstep pipeline */
#define KH    28.853901f           /* 20*log2(e) */

/* 1/(1+exp2(z)) */
__device__ __forceinline__ float hs_neg(float z) {
    float e = __builtin_amdgcn_exp2f(z);
    return __builtin_amdgcn_rcpf(1.0f + e);
}

#define WAITV(N) asm volatile("s_waitcnt vmcnt(" #N ")" ::: "memory")
#define WAITL()  asm volatile("s_waitcnt lgkmcnt(0)" ::: "memory")
/* raw barrier (NOT __syncthreads: that drains vmcnt(0), killing DMA prefetch) */
#define TICK_BARRIER() do {                                   \
    asm volatile("s_waitcnt lgkmcnt(0)" ::: "memory");        \
    __builtin_amdgcn_s_barrier();                             \
    __builtin_amdgcn_sched_barrier(0); } while (0)

/* one 16-step input chunk = 12 f32x4 per lane (48 floats) */
#define DMA_CHUNK(SLOT, C) do {                                                \
    const float* g_ = row + (size_t)(C) * 48;                                  \
    _Pragma("unroll")                                                          \
    for (int j_ = 0; j_ < 12; ++j_) {                                          \
        __builtin_amdgcn_global_load_lds(                                      \
            (const __attribute__((address_space(1))) void*)(g_ + 4 * j_),      \
            (__attribute__((address_space(3))) void*)&s_in[SLOT][j_][0],       \
            16, 0, 0);                                                         \
    } } while (0)

__global__ __launch_bounds__(256, 1)
void xaj_k32_kernel(const float* __restrict__ inp,
                    const float* __restrict__ p_wum,
                    const float* __restrict__ p_wlm,
                    const float* __restrict__ p_wdm,
                    const float* __restrict__ p_c,
                    const float* __restrict__ p_b,
                    const float* __restrict__ p_k1,
                    const float* __restrict__ p_k2,
                    const float* __restrict__ p_k3,
                    float* __restrict__ out)
{
    /* Lockstep tick T: W0->group T, W1->T-1, W2->T-2, W3->T-3 (barrier/tick).
       All handoffs K-scaled (KH*x).
       Rings: W0->W1 (krem,kd1) ring-2; W1->W2 (ku,kd2) ring-2; W2->W3 (kwd)
       ring-2; W0->W3 (wup: f16 Kwu | f16 p) ring-4 -- all barrier-separated. */
    __shared__ f32x4        s_in  [3][12][64];   /* 36 KB input chunk ring */
    __shared__ float        s_krem[2][GROUP][64];
    __shared__ float        s_kd1 [2][GROUP][64];
    __shared__ float        s_ku  [2][GROUP][64];
    __shared__ float        s_kd2 [2][GROUP][64];
    __shared__ float        s_kwd [2][GROUP][64];
    __shared__ unsigned int s_wup [4][GROUP][64];

    const int lane  = threadIdx.x & 63;
    const int wv    = threadIdx.x >> 6;
    const int chain = blockIdx.x * 64 + lane;
    const float* __restrict__ row = inp + (size_t)chain * (3 * T_LEN);
    float* __restrict__ orow      = out + (size_t)chain * T_LEN;

    const float wum = p_wum[0], wlm = p_wlm[0], wdm = p_wdm[0];
    const float cc  = p_c[0],   bb  = p_b[0];
    const float k1  = p_k1[0],  k2  = p_k2[0],  k3 = p_k3[0];

    /* runoff_production called as (wu, wd, wl, p, wum, wdm, wlm, b, c) */
    const float w_total = (wum * 19.9f + 0.1f)
                        + (wdm * 30.0f + 60.0f)
                        + (wlm * 60.0f + 60.0f);
    const float inv_wt = 1.0f / w_total;
    const float c_s = cc * 0.19f + 0.01f;
    const float b_s = bb * 0.3f  + 0.1f;
    const float k1s = k1 * 0.69f + 0.01f;
    const float k2s = k2 * 0.69f + 0.01f;
    const float k3s = k3 * 0.89f + 0.01f;
    const float Kq = k1s + 0.5f * k2s * (1.0f - k1s)
                   + 0.25f * k3s * (1.0f - k1s) * (1.0f - k2s);
    const float C1 = inv_wt / KH;              /* un-K-scale inside ratio */

    float Kst = 0.0f;                          /* K-scaled scan state per wave */
    int s0 = 0, s1 = 1, s2 = 2;                /* input ring slots */

    if (wv == 0) { DMA_CHUNK(0, 0); DMA_CHUNK(1, 1); }

#pragma clang loop unroll(disable)
    for (int T = 0; T < NT; ++T) {
        if (wv == 0) {
            /* ---- W0: wu-chain. Kwu' = Kp - arg*a, arg = KHpet - Kwu ---- */
            if (T < NG) {
                const int g = T;
                WAITV(0);                      /* chunks 2g,2g+1 (issued last
                                                  tick, ~2800cy old): no-wait */
                f32x4 fv[24];
#pragma unroll
                for (int j = 0; j < 12; ++j) fv[j]      = s_in[s0][j][lane];
#pragma unroll
                for (int j = 0; j < 12; ++j) fv[12 + j] = s_in[s1][j][lane];
                WAITL();                       /* reads done before slot reuse */
                __builtin_amdgcn_sched_barrier(0);
                const int c2 = 2 * g + 2, c3 = 2 * g + 3;
                if (c2 < 2 * NG) DMA_CHUNK(s2, c2);
                if (c3 < 2 * NG) DMA_CHUNK(s0, c3);
                float Kwu = Kst;
#pragma unroll
                for (int j = 0; j < GROUP; ++j) {
                    const int k0 = 3 * j, k2i = 3 * j + 2;
                    float pet = fv[k0 >> 2][k0 & 3];
                    float p   = fv[k2i >> 2][k2i & 3];
                    float KHpet = KH * pet, Kp = KH * p;
                    float arg  = KHpet - Kwu;            /* chain head */
                    float a    = hs_neg(arg);            /* h(wu-pet) */
                    float Kwun = fmaf(-arg, a, Kp);      /* chain tail */
                    float Kd1  = Kwun - Kwu;
                    float Ky   = arg + (Kwun - Kp);      /* = arg*(1-a) */
                    float hx   = hs_neg(-Ky);            /* h(pet-et1), ILP */
                    float Krem = hx * Ky;
                    s_krem[g & 1][j][lane] = Krem;
                    s_kd1 [g & 1][j][lane] = Kd1;
                    f16x2 pk = __builtin_amdgcn_cvt_pkrtz(Kwun, p);
                    s_wup[g & 3][j][lane] = __builtin_bit_cast(unsigned int, pk);
                    Kwu = Kwun;
                }
                Kst = Kwu;
                int t0 = s0; s0 = s2; s2 = s1; s1 = t0;  /* rotate ring */
            }
        } else if (wv == 1) {
            /* ---- W1: wl-chain. Kwl' = A - b2*harg ---- */
            if (T >= 1 && T <= NG) {
                const int g = T - 1;
                float Kwl = Kst;
#pragma unroll
                for (int j = 0; j < GROUP; ++j) {
                    float Krem = s_krem[g & 1][j][lane];
                    float Kd1  = s_kd1 [g & 1][j][lane];
                    float hrem = hs_neg(-Krem);          /* h(rem), ILP */
                    float S    = Kwl + Kd1;
                    float A    = fmaf(-hrem, Krem, S);
                    float arg  = Kwl - Krem;             /* chain head */
                    float b2   = hs_neg(arg);            /* h(rem-wl) */
                    float harg = hrem * arg;
                    float Kwln = fmaf(-b2, harg, A);     /* chain tail */
                    float Ket2 = S - Kwln;
                    s_ku [g & 1][j][lane] = Krem - Ket2;
                    s_kd2[g & 1][j][lane] = Kd1 - Ket2;
                    Kwl = Kwln;
                }
                Kst = Kwl;
            }
        } else if (wv == 2) {
            /* ---- W2: wd-chain. Kwd' = A2 - c2*harg ---- */
            if (T >= 2 && T <= NG + 1) {
                const int g = T - 2;
                float Kwd = Kst;
#pragma unroll
                for (int j = 0; j < GROUP; ++j) {
                    float Ku  = s_ku [g & 1][j][lane];
                    float Kd2 = s_kd2[g & 1][j][lane];
                    float hu  = hs_neg(-Ku);             /* h(u), ILP */
                    float S2  = Kwd + Kd2;
                    float A2  = fmaf(-hu, Ku, S2);
                    float arg = Kwd - Ku;                /* chain head */
                    float c2v = hs_neg(arg);             /* h(u-wd) */
                    float harg = hu * arg;
                    float Kwdn = fmaf(-c2v, harg, A2);   /* chain tail */
                    s_kwd[g & 1][j][lane] = Kwdn;
                    Kwd = Kwdn;
                }
                Kst = Kwd;
            }
        } else {
            /* ---- W3: stateless output ---- */
            if (T >= 3) {
                const int g = T - 3;
                float qv[GROUP];
#pragma unroll
                for (int j = 0; j < GROUP; ++j) {
                    unsigned int pw = s_wup[g & 3][j][lane];
                    f16x2 pk = __builtin_bit_cast(f16x2, pw);
                    float Kwu_ = (float)pk[0];
                    float p    = (float)pk[1];
                    float Kwd_ = s_kwd[g & 1][j][lane];
                    float ru = Kwu_ * C1;
                    float rd = Kwd_ * C1;
                    float s2v = fmaf(c_s * ru, ru, (b_s * rd) * rd);
                    float ps = p - s2v;
                    float so = hs_neg(-KH * ps);         /* h(ps) */
                    qv[j] = ps * so * Kq;
                }
                f32x4* o4 = (f32x4*)(orow + (size_t)g * GROUP);
#pragma unroll
                for (int i = 0; i < GROUP / 4; ++i) {
                    f32x4 q = {qv[4*i], qv[4*i+1], qv[4*i+2], qv[4*i+3]};
                    o4[i] = q;
                }
            }
        }
        TICK_BARRIER();
    }
}

extern "C" void kernel_launch(void* const* d_in, const int* in_sizes, int n_in,
                              void* d_out, int out_size, void* d_ws, size_t ws_size,
                              hipStream_t stream) {
    const float* inp = (const float*)d_in[0];
    const int B = out_size / T_LEN;            // 4096
    dim3 block(256), grid(B / 64);
    xaj_k32_kernel<<<grid, block, 0, stream>>>(
        inp,
        (const float*)d_in[1],  // wum
        (const float*)d_in[2],  // wlm
        (const float*)d_in[3],  // wdm
        (const float*)d_in[4],  // c
        (const float*)d_in[5],  // b
        (const float*)d_in[6],  // k1
        (const float*)d_in[7],  // k2
        (const float*)d_in[8],  // k3
        (float*)d_out);
}